// Round 1
// baseline (187.038 us; speedup 1.0000x reference)
//
#include <hip/hip_runtime.h>

#define N_EDGES 1000000
#define N_TILES (N_EDGES / 16)

typedef __attribute__((ext_vector_type(8))) short short8;
typedef __attribute__((ext_vector_type(4))) float floatx4;

__device__ __forceinline__ short f2bf(float f) {
    __bf16 b = (__bf16)f;           // RNE convert, native on gfx950
    return __builtin_bit_cast(short, b);
}

// ---- prep: Wt[n][k] = bf16(gamma[k]*W1[k][n]) (B-operand layout),
//            GB[0..31] = G_n = sum_k gamma[k]W1[k][n], GB[32..63] = Bc_n = sum_k beta[k]W1[k][n]
__global__ void prep_kernel(const float* __restrict__ gamma,
                            const float* __restrict__ beta,
                            const float* __restrict__ W1,
                            unsigned short* __restrict__ Wt,
                            float* __restrict__ GB) {
    const int t = threadIdx.x;  // t = k in [0,256)
    const float g = gamma[t];
    for (int n = 0; n < 32; ++n) {
        float w = g * W1[t * 32 + n];
        Wt[n * 256 + t] = (unsigned short)f2bf(w);
    }
    if (t < 32) {
        float G = 0.f, B = 0.f;
        for (int k = 0; k < 256; ++k) {
            float w = W1[k * 32 + t];
            G = fmaf(gamma[k], w, G);
            B = fmaf(beta[k], w, B);
        }
        GB[t] = G;
        GB[32 + t] = B;
    }
}

// ---- main: 16 edges per wave, MFMA 16x16x32 bf16, LN folded into epilogue
__global__ __launch_bounds__(256) void edgehead_kernel(
    const float* __restrict__ h,
    const int* __restrict__ ep,
    const float* __restrict__ b1,
    const float* __restrict__ W2,
    const float* __restrict__ b2p,
    const unsigned short* __restrict__ Wt,
    const float* __restrict__ GB,
    float* __restrict__ out)
{
    const int lane = threadIdx.x & 63;
    const int c = lane & 15;   // A-row (edge within tile); also B/D column
    const int q = lane >> 4;   // quad
    const int wid = (int)((blockIdx.x * blockDim.x + threadIdx.x) >> 6);
    const int nw = (int)((gridDim.x * blockDim.x) >> 6);

    // B fragments: bf[nt][s] = Wt[(nt*16+c)][32*s + 8*q .. +8)  (k = quad*8+j within step)
    short8 bf[2][8];
#pragma unroll
    for (int nt = 0; nt < 2; ++nt)
#pragma unroll
        for (int s = 0; s < 8; ++s)
            bf[nt][s] = *(const short8*)(Wt + (nt * 16 + c) * 256 + 32 * s + 8 * q);

    const float Gn0 = GB[c],      Gn1 = GB[16 + c];
    const float Bn0 = GB[32 + c] + b1[c];
    const float Bn1 = GB[48 + c] + b1[16 + c];
    const float W20 = W2[c],      W21 = W2[16 + c];
    const float b2  = b2p[0];

    for (int t = wid; t < N_TILES; t += nw) {
        const int e = t * 16 + c;
        const int src = ep[e];
        const int dst = ep[N_EDGES + e];
        const float* hu = h + (long)src * 64 + 8 * q;
        const float* hv = h + (long)dst * 64 + 8 * q;

        // fb[s][j]: s=0 u(b0) 1 u(b1) 2 v(b0) 3 v(b1) 4 |d|(b0) 5 |d|(b1) 6 p(b0) 7 p(b1)
        // lane's A-frag for K-step s is feat[k = 32s + 8q + j], group = s>>1, i = 32*(s&1)+8q+j
        float fb[8][8] __attribute__((aligned(16)));
        *(floatx4*)&fb[0][0] = *(const floatx4*)(hu);
        *(floatx4*)&fb[0][4] = *(const floatx4*)(hu + 4);
        *(floatx4*)&fb[1][0] = *(const floatx4*)(hu + 32);
        *(floatx4*)&fb[1][4] = *(const floatx4*)(hu + 36);
        *(floatx4*)&fb[2][0] = *(const floatx4*)(hv);
        *(floatx4*)&fb[2][4] = *(const floatx4*)(hv + 4);
        *(floatx4*)&fb[3][0] = *(const floatx4*)(hv + 32);
        *(floatx4*)&fb[3][4] = *(const floatx4*)(hv + 36);
#pragma unroll
        for (int j = 0; j < 8; ++j) {
            fb[4][j] = fabsf(fb[0][j] - fb[2][j]);
            fb[5][j] = fabsf(fb[1][j] - fb[3][j]);
            fb[6][j] = fb[0][j] * fb[2][j];
            fb[7][j] = fb[1][j] * fb[3][j];
        }

        float s1 = 0.f, s2 = 0.f;
#pragma unroll
        for (int s = 0; s < 8; ++s)
#pragma unroll
            for (int j = 0; j < 8; ++j) {
                const float f = fb[s][j];
                s1 += f;
                s2 = fmaf(f, f, s2);
            }
        // combine the 4 quads holding edge m = c
        s1 += __shfl_xor(s1, 16); s2 += __shfl_xor(s2, 16);
        s1 += __shfl_xor(s1, 32); s2 += __shfl_xor(s2, 32);
        const float mu = s1 * (1.f / 256.f);
        const float var = fmaf(s2, 1.f / 256.f, -mu * mu);
        const float rs = rsqrtf(var + 1e-5f);

        floatx4 acc0 = {0.f, 0.f, 0.f, 0.f};
        floatx4 acc1 = {0.f, 0.f, 0.f, 0.f};
#pragma unroll
        for (int s = 0; s < 8; ++s) {
            short8 af;
#pragma unroll
            for (int j = 0; j < 8; ++j) af[j] = f2bf(fb[s][j]);
            acc0 = __builtin_amdgcn_mfma_f32_16x16x32_bf16(af, bf[0][s], acc0, 0, 0, 0);
            acc1 = __builtin_amdgcn_mfma_f32_16x16x32_bf16(af, bf[1][s], acc1, 0, 0, 0);
        }

        // D layout: lane holds D[row = 4q + r][col = c]; row = edge, col = n
#pragma unroll
        for (int r = 0; r < 4; ++r) {
            const int srcl = 4 * q + r;            // lanes 0..15 hold edge==lane stats
            const float mu_r = __shfl(mu, srcl);
            const float rs_r = __shfl(rs, srcl);
            float h0 = fmaf(rs_r, fmaf(-mu_r, Gn0, acc0[r]), Bn0); h0 = fmaxf(h0, 0.f);
            float h1 = fmaf(rs_r, fmaf(-mu_r, Gn1, acc1[r]), Bn1); h1 = fmaxf(h1, 0.f);
            float part = fmaf(h0, W20, h1 * W21);
            part += __shfl_xor(part, 1);
            part += __shfl_xor(part, 2);
            part += __shfl_xor(part, 4);
            part += __shfl_xor(part, 8);
            if (c == 0) out[t * 16 + 4 * q + r] = part + b2;
        }
    }
}

extern "C" void kernel_launch(void* const* d_in, const int* in_sizes, int n_in,
                              void* d_out, int out_size, void* d_ws, size_t ws_size,
                              hipStream_t stream) {
    const float* h     = (const float*)d_in[0];
    const int*   ep    = (const int*)d_in[1];
    const float* gamma = (const float*)d_in[2];
    const float* beta  = (const float*)d_in[3];
    const float* W1    = (const float*)d_in[4];
    const float* b1    = (const float*)d_in[5];
    const float* W2    = (const float*)d_in[6];
    const float* b2    = (const float*)d_in[7];
    float* out = (float*)d_out;

    unsigned short* Wt = (unsigned short*)d_ws;               // 32*256*2 = 16384 B
    float* GB = (float*)((char*)d_ws + 16384);                // 64 floats

    prep_kernel<<<1, 256, 0, stream>>>(gamma, beta, W1, Wt, GB);
    edgehead_kernel<<<2048, 256, 0, stream>>>(h, ep, b1, W2, b2, Wt, GB, out);
}

// Round 2
// 153.608 us; speedup vs baseline: 1.2176x; 1.2176x over previous
//
#include <hip/hip_runtime.h>

#define N_EDGES 1000000
#define N_TILES (N_EDGES / 16)
#define N_NODES 100000

typedef __attribute__((ext_vector_type(8))) short short8;
typedef __attribute__((ext_vector_type(4))) float floatx4;

__device__ __forceinline__ short f2bf(float f) {
    __bf16 b = (__bf16)f;           // RNE convert, native on gfx950
    return __builtin_bit_cast(short, b);
}
__device__ __forceinline__ float bf2f(short s) {
    return (float)__builtin_bit_cast(__bf16, s);
}

// ---- h fp32 -> bf16, 8 elems/thread, 800000 threads
__global__ __launch_bounds__(256) void conv_kernel(const float* __restrict__ h,
                                                   unsigned short* __restrict__ hb) {
    const int i = blockIdx.x * blockDim.x + threadIdx.x;
    if (i >= (N_NODES * 64) / 8) return;
    const float* p = h + (long)i * 8;
    floatx4 a = *(const floatx4*)p;
    floatx4 b = *(const floatx4*)(p + 4);
    short8 o;
    o[0] = f2bf(a[0]); o[1] = f2bf(a[1]); o[2] = f2bf(a[2]); o[3] = f2bf(a[3]);
    o[4] = f2bf(b[0]); o[5] = f2bf(b[1]); o[6] = f2bf(b[2]); o[7] = f2bf(b[3]);
    *(short8*)(hb + (long)i * 8) = o;
}

// ---- W prep: one block per output n (32 blocks x 256 threads)
// Wt[n][k] = bf16(gamma[k]*W1[k][n]); GB[n]=sum_k gamma[k]W1[k][n]; GB[32+n]=sum_k beta[k]W1[k][n]
__global__ __launch_bounds__(256) void wprep_kernel(const float* __restrict__ gamma,
                                                    const float* __restrict__ beta,
                                                    const float* __restrict__ W1,
                                                    unsigned short* __restrict__ Wt,
                                                    float* __restrict__ GB) {
    const int n = blockIdx.x;
    const int k = threadIdx.x;
    const float w1 = W1[k * 32 + n];
    float G = gamma[k] * w1;
    float B = beta[k] * w1;
    Wt[n * 256 + k] = (unsigned short)f2bf(G);
    G += __shfl_xor(G, 1);  B += __shfl_xor(B, 1);
    G += __shfl_xor(G, 2);  B += __shfl_xor(B, 2);
    G += __shfl_xor(G, 4);  B += __shfl_xor(B, 4);
    G += __shfl_xor(G, 8);  B += __shfl_xor(B, 8);
    G += __shfl_xor(G, 16); B += __shfl_xor(B, 16);
    G += __shfl_xor(G, 32); B += __shfl_xor(B, 32);
    __shared__ float sG[4], sB[4];
    if ((k & 63) == 0) { sG[k >> 6] = G; sB[k >> 6] = B; }
    __syncthreads();
    if (k == 0) {
        GB[n]      = sG[0] + sG[1] + sG[2] + sG[3];
        GB[32 + n] = sB[0] + sB[1] + sB[2] + sB[3];
    }
}

// ---- main: 16 edges per wave, MFMA 16x16x32 bf16, LN folded into epilogue
__global__ __launch_bounds__(256) void edgehead_kernel(
    const unsigned short* __restrict__ hb,
    const int* __restrict__ ep,
    const float* __restrict__ b1,
    const float* __restrict__ W2,
    const float* __restrict__ b2p,
    const unsigned short* __restrict__ Wt,
    const float* __restrict__ GB,
    float* __restrict__ out)
{
    const int lane = threadIdx.x & 63;
    const int c = lane & 15;   // A-row (edge within tile); also B/D column
    const int q = lane >> 4;   // quad
    const int wid = (int)((blockIdx.x * blockDim.x + threadIdx.x) >> 6);
    const int nw = (int)((gridDim.x * blockDim.x) >> 6);

    // B fragments: bfrag[nt][s] = Wt[(nt*16+c)][32*s + 8*q .. +8)
    short8 bfrag[2][8];
#pragma unroll
    for (int nt = 0; nt < 2; ++nt)
#pragma unroll
        for (int s = 0; s < 8; ++s)
            bfrag[nt][s] = *(const short8*)(Wt + (nt * 16 + c) * 256 + 32 * s + 8 * q);

    const float Gn0 = GB[c],      Gn1 = GB[16 + c];
    const float Bn0 = GB[32 + c] + b1[c];
    const float Bn1 = GB[48 + c] + b1[16 + c];
    const float W20 = W2[c],      W21 = W2[16 + c];
    const float b2  = b2p[0];

    int t = wid;
    if (t >= N_TILES) return;
    int src = ep[t * 16 + c];
    int dst = ep[N_EDGES + t * 16 + c];

    for (; t < N_TILES; t += nw) {
        const unsigned short* pu = hb + (long)src * 64 + 8 * q;
        const unsigned short* pv = hb + (long)dst * 64 + 8 * q;
        // u/v A-fragments straight from memory (k-steps 0..3)
        short8 au0 = *(const short8*)(pu);
        short8 au1 = *(const short8*)(pu + 32);
        short8 av0 = *(const short8*)(pv);
        short8 av1 = *(const short8*)(pv + 32);

        // prefetch next tile's indices (breaks idx->row serial chain)
        {
            const int tn = t + nw;
            const int en = (tn < N_TILES ? tn : t) * 16 + c;
            src = ep[en];
            dst = ep[N_EDGES + en];
        }

        float fu0[8], fu1[8], fv0[8], fv1[8], fd0[8], fd1[8], fp0[8], fp1[8];
#pragma unroll
        for (int j = 0; j < 8; ++j) {
            fu0[j] = bf2f(au0[j]); fu1[j] = bf2f(au1[j]);
            fv0[j] = bf2f(av0[j]); fv1[j] = bf2f(av1[j]);
        }
#pragma unroll
        for (int j = 0; j < 8; ++j) {
            fd0[j] = fabsf(fu0[j] - fv0[j]);
            fd1[j] = fabsf(fu1[j] - fv1[j]);
            fp0[j] = fu0[j] * fv0[j];
            fp1[j] = fu1[j] * fv1[j];
        }
        short8 ad0, ad1, ap0, ap1;
#pragma unroll
        for (int j = 0; j < 8; ++j) {
            ad0[j] = f2bf(fd0[j]); ad1[j] = f2bf(fd1[j]);
            ap0[j] = f2bf(fp0[j]); ap1[j] = f2bf(fp1[j]);
        }

        float s1 = 0.f, s2 = 0.f;
#pragma unroll
        for (int j = 0; j < 8; ++j) {
            s1 += fu0[j] + fu1[j] + fv0[j] + fv1[j] + fd0[j] + fd1[j] + fp0[j] + fp1[j];
            s2 = fmaf(fu0[j], fu0[j], s2); s2 = fmaf(fu1[j], fu1[j], s2);
            s2 = fmaf(fv0[j], fv0[j], s2); s2 = fmaf(fv1[j], fv1[j], s2);
            s2 = fmaf(fd0[j], fd0[j], s2); s2 = fmaf(fd1[j], fd1[j], s2);
            s2 = fmaf(fp0[j], fp0[j], s2); s2 = fmaf(fp1[j], fp1[j], s2);
        }
        // combine the 4 quads holding edge m = c
        s1 += __shfl_xor(s1, 16); s2 += __shfl_xor(s2, 16);
        s1 += __shfl_xor(s1, 32); s2 += __shfl_xor(s2, 32);
        const float mu = s1 * (1.f / 256.f);
        const float var = fmaf(s2, 1.f / 256.f, -mu * mu);
        const float rs = rsqrtf(var + 1e-5f);

        floatx4 acc0 = {0.f, 0.f, 0.f, 0.f};
        floatx4 acc1 = {0.f, 0.f, 0.f, 0.f};
        acc0 = __builtin_amdgcn_mfma_f32_16x16x32_bf16(au0, bfrag[0][0], acc0, 0, 0, 0);
        acc1 = __builtin_amdgcn_mfma_f32_16x16x32_bf16(au0, bfrag[1][0], acc1, 0, 0, 0);
        acc0 = __builtin_amdgcn_mfma_f32_16x16x32_bf16(au1, bfrag[0][1], acc0, 0, 0, 0);
        acc1 = __builtin_amdgcn_mfma_f32_16x16x32_bf16(au1, bfrag[1][1], acc1, 0, 0, 0);
        acc0 = __builtin_amdgcn_mfma_f32_16x16x32_bf16(av0, bfrag[0][2], acc0, 0, 0, 0);
        acc1 = __builtin_amdgcn_mfma_f32_16x16x32_bf16(av0, bfrag[1][2], acc1, 0, 0, 0);
        acc0 = __builtin_amdgcn_mfma_f32_16x16x32_bf16(av1, bfrag[0][3], acc0, 0, 0, 0);
        acc1 = __builtin_amdgcn_mfma_f32_16x16x32_bf16(av1, bfrag[1][3], acc1, 0, 0, 0);
        acc0 = __builtin_amdgcn_mfma_f32_16x16x32_bf16(ad0, bfrag[0][4], acc0, 0, 0, 0);
        acc1 = __builtin_amdgcn_mfma_f32_16x16x32_bf16(ad0, bfrag[1][4], acc1, 0, 0, 0);
        acc0 = __builtin_amdgcn_mfma_f32_16x16x32_bf16(ad1, bfrag[0][5], acc0, 0, 0, 0);
        acc1 = __builtin_amdgcn_mfma_f32_16x16x32_bf16(ad1, bfrag[1][5], acc1, 0, 0, 0);
        acc0 = __builtin_amdgcn_mfma_f32_16x16x32_bf16(ap0, bfrag[0][6], acc0, 0, 0, 0);
        acc1 = __builtin_amdgcn_mfma_f32_16x16x32_bf16(ap0, bfrag[1][6], acc1, 0, 0, 0);
        acc0 = __builtin_amdgcn_mfma_f32_16x16x32_bf16(ap1, bfrag[0][7], acc0, 0, 0, 0);
        acc1 = __builtin_amdgcn_mfma_f32_16x16x32_bf16(ap1, bfrag[1][7], acc1, 0, 0, 0);

        // D layout: lane holds D[row = 4q + r][col = c]; row = edge, col = n
#pragma unroll
        for (int r = 0; r < 4; ++r) {
            const int srcl = 4 * q + r;            // lanes 0..15 hold edge==lane stats
            const float mu_r = __shfl(mu, srcl);
            const float rs_r = __shfl(rs, srcl);
            float h0 = fmaf(rs_r, fmaf(-mu_r, Gn0, acc0[r]), Bn0); h0 = fmaxf(h0, 0.f);
            float h1 = fmaf(rs_r, fmaf(-mu_r, Gn1, acc1[r]), Bn1); h1 = fmaxf(h1, 0.f);
            float part = fmaf(h0, W20, h1 * W21);
            part += __shfl_xor(part, 1);
            part += __shfl_xor(part, 2);
            part += __shfl_xor(part, 4);
            part += __shfl_xor(part, 8);
            if (c == 0) out[t * 16 + 4 * q + r] = part + b2;
        }
    }
}

extern "C" void kernel_launch(void* const* d_in, const int* in_sizes, int n_in,
                              void* d_out, int out_size, void* d_ws, size_t ws_size,
                              hipStream_t stream) {
    const float* h     = (const float*)d_in[0];
    const int*   ep    = (const int*)d_in[1];
    const float* gamma = (const float*)d_in[2];
    const float* beta  = (const float*)d_in[3];
    const float* W1    = (const float*)d_in[4];
    const float* b1    = (const float*)d_in[5];
    const float* W2    = (const float*)d_in[6];
    const float* b2    = (const float*)d_in[7];
    float* out = (float*)d_out;

    unsigned short* hb = (unsigned short*)d_ws;                   // 100000*64*2 = 12,800,000 B
    unsigned short* Wt = (unsigned short*)((char*)d_ws + 12800000);  // 32*256*2 = 16384 B
    float* GB = (float*)((char*)d_ws + 12800000 + 16384);            // 64 floats

    conv_kernel<<<(N_NODES * 64 / 8 + 255) / 256, 256, 0, stream>>>(h, hb);
    wprep_kernel<<<32, 256, 0, stream>>>(gamma, beta, W1, Wt, GB);
    edgehead_kernel<<<2048, 256, 0, stream>>>(hb, ep, b1, W2, b2, Wt, GB, out);
}

// Round 3
// 145.665 us; speedup vs baseline: 1.2840x; 1.0545x over previous
//
#include <hip/hip_runtime.h>

#define N_EDGES 1000000
#define N_TILES (N_EDGES / 16)
#define N_NODES 100000

typedef __attribute__((ext_vector_type(8))) short short8;
typedef __attribute__((ext_vector_type(4))) float floatx4;

__device__ __forceinline__ short f2bf(float f) {
    __bf16 b = (__bf16)f;           // RNE convert, native on gfx950
    return __builtin_bit_cast(short, b);
}
__device__ __forceinline__ float bf2f(short s) {
    return (float)__builtin_bit_cast(__bf16, s);
}

// ---- h fp32 -> bf16, 8 elems/thread
__global__ __launch_bounds__(256) void conv_kernel(const float* __restrict__ h,
                                                   unsigned short* __restrict__ hb) {
    const int i = blockIdx.x * blockDim.x + threadIdx.x;
    if (i >= (N_NODES * 64) / 8) return;
    const float* p = h + (long)i * 8;
    floatx4 a = *(const floatx4*)p;
    floatx4 b = *(const floatx4*)(p + 4);
    short8 o;
    o[0] = f2bf(a[0]); o[1] = f2bf(a[1]); o[2] = f2bf(a[2]); o[3] = f2bf(a[3]);
    o[4] = f2bf(b[0]); o[5] = f2bf(b[1]); o[6] = f2bf(b[2]); o[7] = f2bf(b[3]);
    *(short8*)(hb + (long)i * 8) = o;
}

// ---- W prep: one block per output n (32 blocks x 256 threads)
__global__ __launch_bounds__(256) void wprep_kernel(const float* __restrict__ gamma,
                                                    const float* __restrict__ beta,
                                                    const float* __restrict__ W1,
                                                    unsigned short* __restrict__ Wt,
                                                    float* __restrict__ GB) {
    const int n = blockIdx.x;
    const int k = threadIdx.x;
    const float w1 = W1[k * 32 + n];
    float G = gamma[k] * w1;
    float B = beta[k] * w1;
    Wt[n * 256 + k] = (unsigned short)f2bf(G);
    G += __shfl_xor(G, 1);  B += __shfl_xor(B, 1);
    G += __shfl_xor(G, 2);  B += __shfl_xor(B, 2);
    G += __shfl_xor(G, 4);  B += __shfl_xor(B, 4);
    G += __shfl_xor(G, 8);  B += __shfl_xor(B, 8);
    G += __shfl_xor(G, 16); B += __shfl_xor(B, 16);
    G += __shfl_xor(G, 32); B += __shfl_xor(B, 32);
    __shared__ float sG[4], sB[4];
    if ((k & 63) == 0) { sG[k >> 6] = G; sB[k >> 6] = B; }
    __syncthreads();
    if (k == 0) {
        GB[n]      = sG[0] + sG[1] + sG[2] + sG[3];
        GB[32 + n] = sB[0] + sB[1] + sB[2] + sB[3];
    }
}

// ---- main: 16 edges/wave; MFMA for MLP *and* LN stats; pipelined gather
__global__ __launch_bounds__(256) void edgehead_kernel(
    const unsigned short* __restrict__ hb,
    const int* __restrict__ ep,
    const float* __restrict__ b1,
    const float* __restrict__ W2,
    const float* __restrict__ b2p,
    const unsigned short* __restrict__ Wt,
    const float* __restrict__ GB,
    float* __restrict__ out)
{
    const int lane = threadIdx.x & 63;
    const int c = lane & 15;   // A-row (edge); also B/D column
    const int q = lane >> 4;   // quad
    const int wid = (int)((blockIdx.x * blockDim.x + threadIdx.x) >> 6);
    const int nw = (int)((gridDim.x * blockDim.x) >> 6);

    // B fragments: bfrag[nt][s] = Wt[(nt*16+c)][32*s + 8*q ..)
    short8 bfrag[2][8];
#pragma unroll
    for (int nt = 0; nt < 2; ++nt)
#pragma unroll
        for (int s = 0; s < 8; ++s)
            bfrag[nt][s] = *(const short8*)(Wt + (nt * 16 + c) * 256 + 32 * s + 8 * q);

    short8 ones;
#pragma unroll
    for (int j = 0; j < 8; ++j) ones[j] = (short)0x3F80;   // bf16 1.0

    const float Gn0 = GB[c],      Gn1 = GB[16 + c];
    const float Bn0 = GB[32 + c] + b1[c];
    const float Bn1 = GB[48 + c] + b1[16 + c];
    const float W20 = W2[c],      W21 = W2[16 + c];
    const float b2  = b2p[0];

    int t = wid;
    if (t >= N_TILES) return;

    // --- prologue: rows(t), idx(t+nw)
    int s0 = ep[t * 16 + c];
    int d0 = ep[N_EDGES + t * 16 + c];
    short8 au0 = *(const short8*)(hb + (long)s0 * 64 + 8 * q);
    short8 au1 = *(const short8*)(hb + (long)s0 * 64 + 8 * q + 32);
    short8 av0 = *(const short8*)(hb + (long)d0 * 64 + 8 * q);
    short8 av1 = *(const short8*)(hb + (long)d0 * 64 + 8 * q + 32);
    int t1 = t + nw;
    int e1 = (t1 < N_TILES ? t1 : t) * 16 + c;
    int s1i = ep[e1];
    int d1i = ep[N_EDGES + e1];

    for (; t < N_TILES; t += nw) {
        // issue next tile's row loads (latency overlapped with compute below)
        short8 nu0 = *(const short8*)(hb + (long)s1i * 64 + 8 * q);
        short8 nu1 = *(const short8*)(hb + (long)s1i * 64 + 8 * q + 32);
        short8 nv0 = *(const short8*)(hb + (long)d1i * 64 + 8 * q);
        short8 nv1 = *(const short8*)(hb + (long)d1i * 64 + 8 * q + 32);
        // prefetch idx(t+2nw)
        {
            const int tn = t + 2 * nw;
            const int en = (tn < N_TILES ? tn : t) * 16 + c;
            s1i = ep[en];
            d1i = ep[N_EDGES + en];
        }

        // build |u-v| and u*v fragments in f32, round to bf16
        short8 ad0, ad1, ap0, ap1;
#pragma unroll
        for (int j = 0; j < 8; ++j) {
            const float u0 = bf2f(au0[j]), u1 = bf2f(au1[j]);
            const float v0 = bf2f(av0[j]), v1 = bf2f(av1[j]);
            ad0[j] = f2bf(fabsf(u0 - v0));
            ad1[j] = f2bf(fabsf(u1 - v1));
            ap0[j] = f2bf(u0 * v0);
            ap1[j] = f2bf(u1 * v1);
        }

        floatx4 acc0 = {0.f, 0.f, 0.f, 0.f};
        floatx4 acc1 = {0.f, 0.f, 0.f, 0.f};
        floatx4 asum = {0.f, 0.f, 0.f, 0.f};   // D[m][*] = sum_k feat[m][k]
        floatx4 agrm = {0.f, 0.f, 0.f, 0.f};   // D[m][n] = <feat_m, feat_n>; diag = sum f^2
#pragma unroll
        for (int s = 0; s < 8; ++s) {
            short8 af;
            switch (s) {
                case 0: af = au0; break;
                case 1: af = au1; break;
                case 2: af = av0; break;
                case 3: af = av1; break;
                case 4: af = ad0; break;
                case 5: af = ad1; break;
                case 6: af = ap0; break;
                default: af = ap1; break;
            }
            acc0 = __builtin_amdgcn_mfma_f32_16x16x32_bf16(af, bfrag[0][s], acc0, 0, 0, 0);
            acc1 = __builtin_amdgcn_mfma_f32_16x16x32_bf16(af, bfrag[1][s], acc1, 0, 0, 0);
            asum = __builtin_amdgcn_mfma_f32_16x16x32_bf16(af, ones,       asum, 0, 0, 0);
            agrm = __builtin_amdgcn_mfma_f32_16x16x32_bf16(af, af,         agrm, 0, 0, 0);
        }

        // D layout: lane (c,q) holds D[row=4q+r][col=c]
#pragma unroll
        for (int r = 0; r < 4; ++r) {
            // SS for row m=4q+r sits on the Gram diagonal: lane 20q+r, reg r
            const float ss_r = __shfl(agrm[r], 20 * q + r);
            const float mu_r = asum[r] * (1.f / 256.f);
            const float var  = fmaf(ss_r, 1.f / 256.f, -mu_r * mu_r);
            const float rs_r = rsqrtf(var + 1e-5f);
            float h0 = fmaf(rs_r, fmaf(-mu_r, Gn0, acc0[r]), Bn0); h0 = fmaxf(h0, 0.f);
            float h1 = fmaf(rs_r, fmaf(-mu_r, Gn1, acc1[r]), Bn1); h1 = fmaxf(h1, 0.f);
            float part = fmaf(h0, W20, h1 * W21);
            part += __shfl_xor(part, 1);
            part += __shfl_xor(part, 2);
            part += __shfl_xor(part, 4);
            part += __shfl_xor(part, 8);
            if (c == 0) out[t * 16 + 4 * q + r] = part + b2;
        }

        au0 = nu0; au1 = nu1; av0 = nv0; av1 = nv1;
    }
}

extern "C" void kernel_launch(void* const* d_in, const int* in_sizes, int n_in,
                              void* d_out, int out_size, void* d_ws, size_t ws_size,
                              hipStream_t stream) {
    const float* h     = (const float*)d_in[0];
    const int*   ep    = (const int*)d_in[1];
    const float* gamma = (const float*)d_in[2];
    const float* beta  = (const float*)d_in[3];
    const float* W1    = (const float*)d_in[4];
    const float* b1    = (const float*)d_in[5];
    const float* W2    = (const float*)d_in[6];
    const float* b2    = (const float*)d_in[7];
    float* out = (float*)d_out;

    unsigned short* hb = (unsigned short*)d_ws;                      // 12,800,000 B
    unsigned short* Wt = (unsigned short*)((char*)d_ws + 12800000);  // 16,384 B
    float* GB = (float*)((char*)d_ws + 12800000 + 16384);            // 64 floats

    conv_kernel<<<(N_NODES * 64 / 8 + 255) / 256, 256, 0, stream>>>(h, hb);
    wprep_kernel<<<32, 256, 0, stream>>>(gamma, beta, W1, Wt, GB);
    edgehead_kernel<<<2048, 256, 0, stream>>>(hb, ep, b1, W2, b2, Wt, GB, out);
}

// Round 4
// 138.839 us; speedup vs baseline: 1.3472x; 1.0492x over previous
//
#include <hip/hip_runtime.h>
#include <hip/hip_bf16.h>

#define N_EDGES 1000000
#define N_TILES (N_EDGES / 16)
#define N_NODES 100000

typedef __attribute__((ext_vector_type(8))) short short8;
typedef __attribute__((ext_vector_type(4))) float floatx4;

__device__ __forceinline__ short f2bf(float f) {
    __bf16 b = (__bf16)f;           // RNE convert, native on gfx950
    return __builtin_bit_cast(short, b);
}

// |a-b| and a*b elementwise in bf16 (no f32 round-trip; same RNE results)
union BU { short8 s8; __hip_bfloat162 b2[4]; };
__device__ __forceinline__ void dp8(short8 a, short8 b, short8& d, short8& p) {
    BU ua, ub, ud, up;
    ua.s8 = a; ub.s8 = b;
#pragma unroll
    for (int i = 0; i < 4; ++i) {
        ud.b2[i] = __hsub2(ua.b2[i], ub.b2[i]);
        up.b2[i] = __hmul2(ua.b2[i], ub.b2[i]);
    }
#pragma unroll
    for (int j = 0; j < 8; ++j) ud.s8[j] = (short)(ud.s8[j] & 0x7fff);  // bf16 abs
    d = ud.s8; p = up.s8;
}

// ---- h fp32 -> bf16, 8 elems/thread
__global__ __launch_bounds__(256) void conv_kernel(const float* __restrict__ h,
                                                   unsigned short* __restrict__ hb) {
    const int i = blockIdx.x * blockDim.x + threadIdx.x;
    if (i >= (N_NODES * 64) / 8) return;
    const float* p = h + (long)i * 8;
    floatx4 a = *(const floatx4*)p;
    floatx4 b = *(const floatx4*)(p + 4);
    short8 o;
    o[0] = f2bf(a[0]); o[1] = f2bf(a[1]); o[2] = f2bf(a[2]); o[3] = f2bf(a[3]);
    o[4] = f2bf(b[0]); o[5] = f2bf(b[1]); o[6] = f2bf(b[2]); o[7] = f2bf(b[3]);
    *(short8*)(hb + (long)i * 8) = o;
}

// ---- W prep: one block per output n (32 blocks x 256 threads)
__global__ __launch_bounds__(256) void wprep_kernel(const float* __restrict__ gamma,
                                                    const float* __restrict__ beta,
                                                    const float* __restrict__ W1,
                                                    unsigned short* __restrict__ Wt,
                                                    float* __restrict__ GB) {
    const int n = blockIdx.x;
    const int k = threadIdx.x;
    const float w1 = W1[k * 32 + n];
    float G = gamma[k] * w1;
    float B = beta[k] * w1;
    Wt[n * 256 + k] = (unsigned short)f2bf(G);
    G += __shfl_xor(G, 1);  B += __shfl_xor(B, 1);
    G += __shfl_xor(G, 2);  B += __shfl_xor(B, 2);
    G += __shfl_xor(G, 4);  B += __shfl_xor(B, 4);
    G += __shfl_xor(G, 8);  B += __shfl_xor(B, 8);
    G += __shfl_xor(G, 16); B += __shfl_xor(B, 16);
    G += __shfl_xor(G, 32); B += __shfl_xor(B, 32);
    __shared__ float sG[4], sB[4];
    if ((k & 63) == 0) { sG[k >> 6] = G; sB[k >> 6] = B; }
    __syncthreads();
    if (k == 0) {
        GB[n]      = sG[0] + sG[1] + sG[2] + sG[3];
        GB[32 + n] = sB[0] + sB[1] + sB[2] + sB[3];
    }
}

// ---- main: 16 edges/wave; MFMA for MLP, LN stats, AND final W2 dot
__global__ __launch_bounds__(256) void edgehead_kernel(
    const unsigned short* __restrict__ hb,
    const int* __restrict__ ep,
    const float* __restrict__ b1,
    const float* __restrict__ W2,
    const float* __restrict__ b2p,
    const unsigned short* __restrict__ Wt,
    const float* __restrict__ GB,
    float* __restrict__ out)
{
    const int lane = threadIdx.x & 63;
    const int c = lane & 15;   // A-row index; D column
    const int q = lane >> 4;   // quad
    const int wid = (int)((blockIdx.x * blockDim.x + threadIdx.x) >> 6);
    const int nw = (int)((gridDim.x * blockDim.x) >> 6);

    // B fragments: bfrag[nt][s] = Wt[(nt*16+c)][32*s + 8*q ..)
    short8 bfrag[2][8];
#pragma unroll
    for (int nt = 0; nt < 2; ++nt)
#pragma unroll
        for (int s = 0; s < 8; ++s)
            bfrag[nt][s] = *(const short8*)(Wt + (nt * 16 + c) * 256 + 32 * s + 8 * q);

    short8 ones;
#pragma unroll
    for (int j = 0; j < 8; ++j) ones[j] = (short)0x3F80;   // bf16 1.0

    // selector B for the final dot: B[8q+j][c] = (c == 4q+(j&3)) ? 1 : 0
    short8 wsel;
#pragma unroll
    for (int j = 0; j < 8; ++j) wsel[j] = (c == 4 * q + (j & 3)) ? (short)0x3F80 : (short)0;

    const float Gn0 = GB[c],      Gn1 = GB[16 + c];
    const float Bn0 = GB[32 + c] + b1[c];
    const float Bn1 = GB[48 + c] + b1[16 + c];
    const float W20 = W2[c],      W21 = W2[16 + c];
    const float b2  = b2p[0];

    int t = wid;
    if (t >= N_TILES) return;

    // --- prologue: rows(t), idx(t+nw)
    int s0 = ep[t * 16 + c];
    int d0 = ep[N_EDGES + t * 16 + c];
    short8 au0 = *(const short8*)(hb + (long)s0 * 64 + 8 * q);
    short8 au1 = *(const short8*)(hb + (long)s0 * 64 + 8 * q + 32);
    short8 av0 = *(const short8*)(hb + (long)d0 * 64 + 8 * q);
    short8 av1 = *(const short8*)(hb + (long)d0 * 64 + 8 * q + 32);
    int t1 = t + nw;
    int e1 = (t1 < N_TILES ? t1 : t) * 16 + c;
    int s1i = ep[e1];
    int d1i = ep[N_EDGES + e1];

    for (; t < N_TILES; t += nw) {
        // issue next tile's row loads (latency overlapped with compute below)
        short8 nu0 = *(const short8*)(hb + (long)s1i * 64 + 8 * q);
        short8 nu1 = *(const short8*)(hb + (long)s1i * 64 + 8 * q + 32);
        short8 nv0 = *(const short8*)(hb + (long)d1i * 64 + 8 * q);
        short8 nv1 = *(const short8*)(hb + (long)d1i * 64 + 8 * q + 32);
        // prefetch idx(t+2nw)
        {
            const int tn = t + 2 * nw;
            const int en = (tn < N_TILES ? tn : t) * 16 + c;
            s1i = ep[en];
            d1i = ep[N_EDGES + en];
        }

        // feat build fully in bf16 (packed)
        short8 ad0, ad1, ap0, ap1;
        dp8(au0, av0, ad0, ap0);
        dp8(au1, av1, ad1, ap1);

        floatx4 acc0 = {0.f, 0.f, 0.f, 0.f};
        floatx4 acc1 = {0.f, 0.f, 0.f, 0.f};
        floatx4 asum = {0.f, 0.f, 0.f, 0.f};   // row sums (same in every column lane)
        floatx4 agrm = {0.f, 0.f, 0.f, 0.f};   // Gram; diagonal = sum of squares
#pragma unroll
        for (int s = 0; s < 8; ++s) {
            short8 af;
            switch (s) {
                case 0: af = au0; break;
                case 1: af = au1; break;
                case 2: af = av0; break;
                case 3: af = av1; break;
                case 4: af = ad0; break;
                case 5: af = ad1; break;
                case 6: af = ap0; break;
                default: af = ap1; break;
            }
            acc0 = __builtin_amdgcn_mfma_f32_16x16x32_bf16(af, bfrag[0][s], acc0, 0, 0, 0);
            acc1 = __builtin_amdgcn_mfma_f32_16x16x32_bf16(af, bfrag[1][s], acc1, 0, 0, 0);
            asum = __builtin_amdgcn_mfma_f32_16x16x32_bf16(af, ones,       asum, 0, 0, 0);
            agrm = __builtin_amdgcn_mfma_f32_16x16x32_bf16(af, af,         agrm, 0, 0, 0);
        }

        // LN epilogue + hmid*W2 packed as A-fragment for the selector MFMA.
        // acc0[r] = pre-LN hmid[edge=4q+r][n=c]; acc1[r] = [n=16+c].
        float ss[4];
#pragma unroll
        for (int r = 0; r < 4; ++r) ss[r] = __shfl(agrm[r], 20 * q + r);
        short8 af2;
#pragma unroll
        for (int r = 0; r < 4; ++r) {
            const float mu  = asum[r] * (1.f / 256.f);
            const float var = fmaf(ss[r], 1.f / 256.f, -mu * mu);
            const float rs  = rsqrtf(var + 1e-5f);
            float h0 = fmaf(rs, fmaf(-mu, Gn0, acc0[r]), Bn0); h0 = fmaxf(h0, 0.f);
            float h1 = fmaf(rs, fmaf(-mu, Gn1, acc1[r]), Bn1); h1 = fmaxf(h1, 0.f);
            af2[r]     = f2bf(h0 * W20);
            af2[4 + r] = f2bf(h1 * W21);
        }
        floatx4 dfin = {0.f, 0.f, 0.f, 0.f};
        dfin = __builtin_amdgcn_mfma_f32_16x16x32_bf16(af2, wsel, dfin, 0, 0, 0);
        // lane (c,q) reg r = hmidW2[c][4q+r] + hmidW2[c][4q+r+16]
        float part = (dfin[0] + dfin[1]) + (dfin[2] + dfin[3]);
        part += __shfl_xor(part, 16);
        part += __shfl_xor(part, 32);
        if (q == 0) out[t * 16 + c] = part + b2;   // coalesced 64B store

        au0 = nu0; au1 = nu1; av0 = nv0; av1 = nv1;
    }
}

extern "C" void kernel_launch(void* const* d_in, const int* in_sizes, int n_in,
                              void* d_out, int out_size, void* d_ws, size_t ws_size,
                              hipStream_t stream) {
    const float* h     = (const float*)d_in[0];
    const int*   ep    = (const int*)d_in[1];
    const float* gamma = (const float*)d_in[2];
    const float* beta  = (const float*)d_in[3];
    const float* W1    = (const float*)d_in[4];
    const float* b1    = (const float*)d_in[5];
    const float* W2    = (const float*)d_in[6];
    const float* b2    = (const float*)d_in[7];
    float* out = (float*)d_out;

    unsigned short* hb = (unsigned short*)d_ws;                      // 12,800,000 B
    unsigned short* Wt = (unsigned short*)((char*)d_ws + 12800000);  // 16,384 B
    float* GB = (float*)((char*)d_ws + 12800000 + 16384);            // 64 floats

    conv_kernel<<<(N_NODES * 64 / 8 + 255) / 256, 256, 0, stream>>>(h, hb);
    wprep_kernel<<<32, 256, 0, stream>>>(gamma, beta, W1, Wt, GB);
    edgehead_kernel<<<2048, 256, 0, stream>>>(hb, ep, b1, W2, b2, Wt, GB, out);
}